// Round 5
// baseline (1224.781 us; speedup 1.0000x reference)
//
#include <hip/hip_runtime.h>
#include <math.h>

// B=4096, S=64, H=256, 2 GRU layers.
// 32 clusters x 8 WGs (=256 WGs, 1/CU). Weight slice (144 KB fp16) LDS-resident.
// PING-PONG: each cluster's 128 rows = two independent 64-row sub-batches (A,B).
// Per step: phaseA -> arriveA -> phaseB -> arriveB. Barrier A's IC round-trip
// is hidden under phaseB's compute (and vice versa) -> barrier off critical path.
// h-state exchange unchanged from R4 (write-through sc0 sc1 stores, agent loads).
#define NCL 32
#define CW  8
#define BTC 128
#define NT  512
#define SS  64
#define HH  256

typedef __attribute__((ext_vector_type(8))) _Float16 half8;
typedef __attribute__((ext_vector_type(4))) float    f32x4;

__device__ __forceinline__ float sigmoidf_(float v){
    return __builtin_amdgcn_rcpf(1.f + __expf(-v));
}
__device__ __forceinline__ float tanhf_(float x){
    return 1.f - 2.f*__builtin_amdgcn_rcpf(1.f + __expf(2.f*x));
}
// h load: 16B via two agent-scope relaxed u64 atomic loads (L1/L2 bypass -> IC)
__device__ __forceinline__ half8 ldA(const _Float16* p){
    union { unsigned long long u[2]; half8 h; } r;
    const unsigned long long* q = (const unsigned long long*)p;
    r.u[0] = __hip_atomic_load(q,   __ATOMIC_RELAXED, __HIP_MEMORY_SCOPE_AGENT);
    r.u[1] = __hip_atomic_load(q+1, __ATOMIC_RELAXED, __HIP_MEMORY_SCOPE_AGENT);
    return r.h;
}
// h store: 2B write-through to IC (sc0 sc1) — leaves no dirty L2 line
__device__ __forceinline__ void stH(_Float16* p, float v){
    _Float16 hv = (_Float16)v;
    asm volatile("global_store_short %0, %1, off sc0 sc1" :: "v"(p), "v"(hv));
}

// LDS weight layout: halfs offset = mat*24576 + ntl*4096 + kt*512 + lane*8
// mat: 0=Whh0 1=Wih1 2=Whh1 ; ntl = type*2 + hv (type 0=r,1=z,2=n)
#define WOFF(mat,ntl,kt) ((mat)*24576 + (ntl)*4096 + (kt)*512)

__global__ void zero_flags(int* f){
    int i = blockIdx.x*blockDim.x + threadIdx.x;
    if (i < NCL*2*SS) f[i] = 0;
}

// ---- interval 0 (closed-form): h1n(0)=0; h0n(1)=GRU(x(bit0), 0) ----
#define IV0(SBX, HR0)                                                         \
  {                                                                           \
    const int rb = (SBX)*64;                                                  \
    _Float16* wp1 = H1 + (rb + 16*mp + 4*quad)*HH + ucol;                     \
    _Pragma("unroll")                                                         \
    for (int reg=0;reg<4;++reg) stH(wp1 + reg*HH, 0.f);                       \
    _Float16* wp0 = H0 + (BTC*HH) + (rb + 16*mp + 4*quad)*HH + ucol;          \
    _Pragma("unroll")                                                         \
    for (int reg=0;reg<4;++reg){                                              \
        int rowL = rb + 16*mp + 4*quad + reg;                                 \
        int bit = (int)(bitsM[rowL] & 1ull);                                  \
        float gr = bit?g0w[1]:g0w[0];                                         \
        float gz = bit?g0w[3]:g0w[2];                                         \
        float gn = bit?g0w[5]:g0w[4];                                         \
        float r = sigmoidf_(gr);                                              \
        float z = sigmoidf_(gz);                                              \
        float n = tanhf_(gn);                                                 \
        float hnew = (1.f-z)*n;                                               \
        (HR0)[reg] = hnew;                                                    \
        stH(wp0 + reg*HH, hnew);                                              \
    }                                                                         \
  }

// ---- one pipelined phase for sub-batch SBX at interval i ----
#define PHASE(SBX, FLG, HR0, HR1)                                             \
  {                                                                           \
    const int rb = (SBX)*64;                                                  \
    if (t==0){ int guard=0;                                                   \
      while(__hip_atomic_load(&(FLG)[i-1],__ATOMIC_RELAXED,__HIP_MEMORY_SCOPE_AGENT) < CW){ \
        __builtin_amdgcn_s_sleep(1); if (++guard > (1<<20)) break; } }        \
    __syncthreads();                                                          \
    const int s = i-1;                                                        \
    half8 hvv = {};                                                           \
    if (sb == (SBX)) hvv = ldA(H1 + (s&1)*(BTC*HH) + srow*HH + cs*8);         \
    const _Float16* Hs0 = H0 + (i&1)*(BTC*HH)     + (rb + 16*mp + lm)*HH;     \
    const _Float16* Hs1 = H1 + ((i-1)&1)*(BTC*HH) + (rb + 16*mp + lm)*HH;     \
    half8 A0[8], A1[8];                                                       \
    _Pragma("unroll")                                                         \
    for (int kt=0;kt<8;++kt){                                                 \
        A0[kt] = ldA(Hs0 + kt*32 + quad*8);                                   \
        A1[kt] = ldA(Hs1 + kt*32 + quad*8);                                   \
    }                                                                         \
    if (sb == (SBX)){                                                         \
        float s0=0.f, s1=0.f;                                                 \
        _Pragma("unroll")                                                     \
        for (int e=0;e<8;++e){ float f=(float)hvv[e]; s0+=f*wl0[e]; s1+=f*wl1[e]; } \
        _Pragma("unroll")                                                     \
        for (int off=16; off>0; off>>=1){ s0+=__shfl_xor(s0,off,32); s1+=__shfl_xor(s1,off,32); } \
        float l0=s0+bl0, l1=s1+bl1;                                           \
        bool  ev  = (s & 1) == 0;                                             \
        float low = -16.f + (float)(s>>1);                                    \
        float cnt = ev ? nup : ndn;                                           \
        float mocc = (16.f > cnt) ? 1.f : 0.f;                                \
        float mun  = (low  < cnt) ? 1.f : 0.f;                                \
        float mx = fmaxf(l0,l1);                                              \
        float e0 = __expf(l0-mx), e1 = __expf(l1-mx);                         \
        float inv = __builtin_amdgcn_rcpf(e0+e1);                             \
        float a0s = __builtin_amdgcn_sqrtf(e0*inv)*mun;                       \
        float a1s = __builtin_amdgcn_sqrtf(e1*inv)*mocc;                      \
        float nrm = __builtin_amdgcn_sqrtf(a0s*a0s + a1s*a1s);                \
        float den = fmaxf(nrm, 1e-12f);                                       \
        float rden = __builtin_amdgcn_rcpf(den);                              \
        a0s*=rden; a1s*=rden;                                                 \
        const float PI_F = 3.14159265358979323846f;                           \
        float p0 = PI_F*l0*__builtin_amdgcn_rcpf(1.f+fabsf(l0));              \
        float p1 = PI_F*l1*__builtin_amdgcn_rcpf(1.f+fabsf(l1));              \
        int bit = (int)((bitsM[srow] >> s) & 1ull);                           \
        amp *= bit ? a1s : a0s;                                               \
        ph  += bit ? p1 : p0;                                                 \
        if (ev) nup += (float)bit; else ndn += (float)bit;                    \
    }                                                                         \
    f32x4 g0r={},g0z={},g0n={}, aR={},aZ={},aNI={},aNH={};                    \
    _Pragma("unroll")                                                         \
    for (int kt=0;kt<8;++kt){                                                 \
        half8 b0r = *(const half8*)(wlds + WOFF(0, 0+hv, kt) + L*8);          \
        half8 b0z = *(const half8*)(wlds + WOFF(0, 2+hv, kt) + L*8);          \
        half8 b0n = *(const half8*)(wlds + WOFF(0, 4+hv, kt) + L*8);          \
        half8 b1r = *(const half8*)(wlds + WOFF(1, 0+hv, kt) + L*8);          \
        half8 b1z = *(const half8*)(wlds + WOFF(1, 2+hv, kt) + L*8);          \
        half8 b1n = *(const half8*)(wlds + WOFF(1, 4+hv, kt) + L*8);          \
        half8 b2r = *(const half8*)(wlds + WOFF(2, 0+hv, kt) + L*8);          \
        half8 b2z = *(const half8*)(wlds + WOFF(2, 2+hv, kt) + L*8);          \
        half8 b2n = *(const half8*)(wlds + WOFF(2, 4+hv, kt) + L*8);          \
        g0r = __builtin_amdgcn_mfma_f32_16x16x32_f16(A0[kt], b0r, g0r,0,0,0); \
        g0z = __builtin_amdgcn_mfma_f32_16x16x32_f16(A0[kt], b0z, g0z,0,0,0); \
        g0n = __builtin_amdgcn_mfma_f32_16x16x32_f16(A0[kt], b0n, g0n,0,0,0); \
        aR  = __builtin_amdgcn_mfma_f32_16x16x32_f16(A0[kt], b1r, aR ,0,0,0); \
        aZ  = __builtin_amdgcn_mfma_f32_16x16x32_f16(A0[kt], b1z, aZ ,0,0,0); \
        aNI = __builtin_amdgcn_mfma_f32_16x16x32_f16(A0[kt], b1n, aNI,0,0,0); \
        aR  = __builtin_amdgcn_mfma_f32_16x16x32_f16(A1[kt], b2r, aR ,0,0,0); \
        aZ  = __builtin_amdgcn_mfma_f32_16x16x32_f16(A1[kt], b2z, aZ ,0,0,0); \
        aNH = __builtin_amdgcn_mfma_f32_16x16x32_f16(A1[kt], b2n, aNH,0,0,0); \
    }                                                                         \
    {                                                                         \
        _Float16* wp = H1 + (i&1)*(BTC*HH) + (rb + 16*mp + 4*quad)*HH + ucol; \
        _Pragma("unroll")                                                     \
        for (int reg=0;reg<4;++reg){                                          \
            float r = sigmoidf_(aR[reg]);                                     \
            float z = sigmoidf_(aZ[reg]);                                     \
            float n = tanhf_(aNI[reg] + r*aNH[reg]);                          \
            float hnew = (1.f-z)*n + z*(HR1)[reg];                            \
            (HR1)[reg] = hnew;                                                \
            stH(wp + reg*HH, hnew);                                           \
        }                                                                     \
    }                                                                         \
    if (i < SS-1){                                                            \
        _Float16* wp = H0 + ((i+1)&1)*(BTC*HH) + (rb + 16*mp + 4*quad)*HH + ucol; \
        _Pragma("unroll")                                                     \
        for (int reg=0;reg<4;++reg){                                          \
            int rowL = rb + 16*mp + 4*quad + reg;                             \
            int bit = (int)((bitsM[rowL] >> i) & 1ull);                       \
            float gr = bit?g0w[1]:g0w[0];                                     \
            float gz = bit?g0w[3]:g0w[2];                                     \
            float gn = bit?g0w[5]:g0w[4];                                     \
            float r = sigmoidf_(gr + g0r[reg]);                               \
            float z = sigmoidf_(gz + g0z[reg]);                               \
            float n = tanhf_(gn + r*g0n[reg]);                                \
            float hnew = (1.f-z)*n + z*(HR0)[reg];                            \
            (HR0)[reg] = hnew;                                                \
            stH(wp + reg*HH, hnew);                                           \
        }                                                                     \
    }                                                                         \
    asm volatile("s_waitcnt vmcnt(0)" ::: "memory");                          \
    __syncthreads();                                                          \
    if (t==0)                                                                 \
        __hip_atomic_fetch_add(&(FLG)[i],1,__ATOMIC_RELAXED,__HIP_MEMORY_SCOPE_AGENT); \
  }

__global__ __launch_bounds__(NT,2) void rnn_cluster(
    const int*   __restrict__ x,
    const float* __restrict__ Wih0,
    const float* __restrict__ Whh0,
    const float* __restrict__ Wih1,
    const float* __restrict__ Whh1,
    const float* __restrict__ Wl,
    const float* __restrict__ bl,
    float*       __restrict__ out,
    int*         __restrict__ flags,  // (NCL, 2, SS) zeroed per launch
    _Float16*    __restrict__ Hbuf)   // 2 layers x NCL x 2 bufs x 128x256 halfs
{
    __shared__ _Float16 wlds[3*6*8*64*8];          // 147456 B
    __shared__ unsigned long long bitsM[BTC];

    const int t   = threadIdx.x;
    const int c   = blockIdx.x & (NCL-1);
    const int j   = blockIdx.x >> 5;               // member 0..7
    const int L   = t & 63;
    const int w   = t >> 6;
    const int lm  = L & 15, quad = L >> 4;
    const int mp  = w >> 1, hv = w & 1;
    const int ucol = j*32 + hv*16 + lm;            // this lane's owned unit (col)

    _Float16* H0 = Hbuf + (size_t)c*(2*BTC*HH);
    _Float16* H1 = Hbuf + (size_t)(NCL + c)*(2*BTC*HH);
    int* flgA = flags + c*(2*SS);
    int* flgB = flgA + SS;

    // ---- pack weight slice into LDS (once) ----
    for (int idx = t; idx < 3*6*8*64; idx += NT){
        int lane = idx & 63;
        int kt   = (idx >> 6) & 7;
        int ntl  = (idx >> 9) % 6;
        int mat  = idx / 3072;
        const float* W = (mat==0) ? Whh0 : (mat==1) ? Wih1 : Whh1;
        int g  = (ntl>>1)*HH + j*32 + (ntl&1)*16 + (lane & 15);
        int kb = kt*32 + (lane>>4)*8;
        _Float16* d = wlds + (size_t)idx*8;
        #pragma unroll
        for (int e=0;e<8;++e) d[e] = (_Float16)W[g*HH + kb + e];
    }
    if (t < BTC){
        unsigned long long m = 0;
        const int* xr = x + (size_t)(c*BTC + t)*SS;
        for (int s=0;s<SS;++s) if (xr[s] > 0) m |= (1ull<<s);
        bitsM[t] = m;
    }

    float g0w[6];
    { int ug = ucol;
      g0w[0]=Wih0[ug*2+0];        g0w[1]=Wih0[ug*2+1];
      g0w[2]=Wih0[(ug+HH)*2+0];   g0w[3]=Wih0[(ug+HH)*2+1];
      g0w[4]=Wih0[(ug+2*HH)*2+0]; g0w[5]=Wih0[(ug+2*HH)*2+1]; }

    // sampling: waves 0-3 own sub-batch A rows, waves 4-7 own B rows.
    // 8 rows/WG/sub-batch, 32 lanes cooperate per row (state replicated).
    const int sb   = (t >= NT/2) ? 1 : 0;
    const int srow = sb*64 + j*8 + ((t>>5) & 7);   // cluster row this thread samples
    const int cs   = t & 31;
    float wl0[8], wl1[8];
    #pragma unroll
    for (int e=0;e<8;++e){ wl0[e]=Wl[cs*8+e]; wl1[e]=Wl[HH+cs*8+e]; }
    const float bl0=bl[0], bl1=bl[1];

    float hr0A[4]={}, hr1A[4]={}, hr0B[4]={}, hr1B[4]={};
    float amp=1.f, ph=0.f, nup=0.f, ndn=0.f;

    __syncthreads();

    // ---- interval 0 for both sub-batches ----
    IV0(0, hr0A)
    IV0(1, hr0B)
    asm volatile("s_waitcnt vmcnt(0)" ::: "memory");   // write-throughs at IC
    __syncthreads();
    if (t==0){
        __hip_atomic_fetch_add(&flgA[0],1,__ATOMIC_RELAXED,__HIP_MEMORY_SCOPE_AGENT);
        __hip_atomic_fetch_add(&flgB[0],1,__ATOMIC_RELAXED,__HIP_MEMORY_SCOPE_AGENT);
    }

    for (int i=1;i<SS;++i){
        PHASE(0, flgA, hr0A, hr1A)   // barrier B(i-1) propagates under this
        PHASE(1, flgB, hr0B, hr1B)   // barrier A(i) propagates under this
    }

    // ---- epilogue: wait both bar(63), sample s=63 ----
    if (t==0){
        int guard=0;
        while(__hip_atomic_load(&flgA[SS-1],__ATOMIC_RELAXED,__HIP_MEMORY_SCOPE_AGENT) < CW){
            __builtin_amdgcn_s_sleep(1);
            if (++guard > (1<<20)) break;
        }
        guard=0;
        while(__hip_atomic_load(&flgB[SS-1],__ATOMIC_RELAXED,__HIP_MEMORY_SCOPE_AGENT) < CW){
            __builtin_amdgcn_s_sleep(1);
            if (++guard > (1<<20)) break;
        }
    }
    __syncthreads();
    {
        const int s = SS-1;
        half8 hvv = ldA(H1 + (s&1)*(BTC*HH) + srow*HH + cs*8);
        float s0=0.f, s1=0.f;
        #pragma unroll
        for (int e=0;e<8;++e){ float f=(float)hvv[e]; s0+=f*wl0[e]; s1+=f*wl1[e]; }
        #pragma unroll
        for (int off=16; off>0; off>>=1){ s0+=__shfl_xor(s0,off,32); s1+=__shfl_xor(s1,off,32); }
        float l0=s0+bl0, l1=s1+bl1;
        bool  ev  = (s & 1) == 0;
        float low = -16.f + (float)(s>>1);
        float cnt = ev ? nup : ndn;
        float mocc = (16.f > cnt) ? 1.f : 0.f;
        float mun  = (low  < cnt) ? 1.f : 0.f;
        float mx = fmaxf(l0,l1);
        float e0 = __expf(l0-mx), e1 = __expf(l1-mx);
        float inv = __builtin_amdgcn_rcpf(e0+e1);
        float a0s = __builtin_amdgcn_sqrtf(e0*inv)*mun;
        float a1s = __builtin_amdgcn_sqrtf(e1*inv)*mocc;
        float nrm = __builtin_amdgcn_sqrtf(a0s*a0s + a1s*a1s);
        float den = fmaxf(nrm, 1e-12f);
        float rden = __builtin_amdgcn_rcpf(den);
        a0s*=rden; a1s*=rden;
        const float PI_F = 3.14159265358979323846f;
        float p0 = PI_F*l0*__builtin_amdgcn_rcpf(1.f+fabsf(l0));
        float p1 = PI_F*l1*__builtin_amdgcn_rcpf(1.f+fabsf(l1));
        int bit = (int)((bitsM[srow] >> s) & 1ull);
        amp *= bit ? a1s : a0s;
        ph  += bit ? p1 : p0;
    }
    if (cs == 0) out[c*BTC + srow] = amp * cosf(ph);
}

extern "C" void kernel_launch(void* const* d_in, const int* in_sizes, int n_in,
                              void* d_out, int out_size, void* d_ws, size_t ws_size,
                              hipStream_t stream) {
    (void)in_sizes; (void)n_in; (void)out_size; (void)ws_size;
    const int*   x    = (const int*)d_in[0];
    const float* Wih0 = (const float*)d_in[1];
    const float* Whh0 = (const float*)d_in[2];
    const float* Wih1 = (const float*)d_in[3];
    const float* Whh1 = (const float*)d_in[4];
    const float* Wl   = (const float*)d_in[5];
    const float* bl   = (const float*)d_in[6];

    int*      flags = (int*)d_ws;                         // 16 KB used, 64 KB reserved
    _Float16* Hbuf  = (_Float16*)((char*)d_ws + 65536);   // 8 MB h state

    zero_flags<<<(NCL*2*SS + 255)/256, 256, 0, stream>>>(flags);
    rnn_cluster<<<NCL*CW, NT, 0, stream>>>(x, Wih0, Whh0, Wih1, Whh1, Wl, bl,
                                           (float*)d_out, flags, Hbuf);
}

// Round 6
// 945.617 us; speedup vs baseline: 1.2952x; 1.2952x over previous
//
#include <hip/hip_runtime.h>
#include <math.h>

// B=4096, S=64, H=256, 2 GRU layers.
// 32 clusters x 8 WGs (=256 WGs, 1/CU). Weight slice (144 KB fp16) LDS-resident.
// R4 schedule (ONE cluster barrier + ONE fused {A-load -> 3 GEMMs} phase/step).
// This round: A-operand reads switch from relaxed-ATOMIC 8B loads (which the
// backend serializes) to plain asm global_load_dwordx4 sc0 sc1 (cache-bypass,
// IC-coherent) issued in BATCHES with counted s_waitcnt vmcnt(N) + reg pinning.
#define NCL 32
#define CW  8
#define BTC 128
#define NT  512
#define SS  64
#define HH  256

typedef __attribute__((ext_vector_type(8))) _Float16 half8;
typedef __attribute__((ext_vector_type(4))) float    f32x4;

__device__ __forceinline__ float sigmoidf_(float v){
    return __builtin_amdgcn_rcpf(1.f + __expf(-v));
}
__device__ __forceinline__ float tanhf_(float x){
    return 1.f - 2.f*__builtin_amdgcn_rcpf(1.f + __expf(2.f*x));
}

// 16B cache-bypassing load (reads the IC coherence point). Result NOT ready
// until a subsequent s_waitcnt vmcnt(N) that pins the dest regs ("+v").
__device__ __forceinline__ half8 ldA16(const _Float16* p){
    half8 r;
    asm volatile("global_load_dwordx4 %0, %1, off sc0 sc1" : "=v"(r) : "v"(p));
    return r;
}
// 2B write-through to IC (no dirty L2 line)
__device__ __forceinline__ void stH(_Float16* p, float v){
    _Float16 hv = (_Float16)v;
    asm volatile("global_store_short %0, %1, off sc0 sc1" :: "v"(p), "v"(hv));
}

// LDS weight layout: halfs offset = mat*24576 + ntl*4096 + kt*512 + lane*8
// mat: 0=Whh0 1=Wih1 2=Whh1 ; ntl = type*2 + hv (type 0=r,1=z,2=n)
#define WOFF(mat,ntl,kt) ((mat)*24576 + (ntl)*4096 + (kt)*512)

__global__ void zero_flags(int* f){
    int i = blockIdx.x*blockDim.x + threadIdx.x;
    if (i < NCL*SS) f[i] = 0;
}

// counted wait + pin 16 A-regs of a chunk + scheduling fence
#define WAIT_PIN_CHUNK(NSTR, A0c, A1c)                                        \
    asm volatile("s_waitcnt vmcnt(" NSTR ")"                                  \
      : "+v"(A0c[0][0]),"+v"(A0c[0][1]),"+v"(A0c[1][0]),"+v"(A0c[1][1]),      \
        "+v"(A0c[2][0]),"+v"(A0c[2][1]),"+v"(A0c[3][0]),"+v"(A0c[3][1]),      \
        "+v"(A1c[0][0]),"+v"(A1c[0][1]),"+v"(A1c[1][0]),"+v"(A1c[1][1]),      \
        "+v"(A1c[2][0]),"+v"(A1c[2][1]),"+v"(A1c[3][0]),"+v"(A1c[3][1])       \
      :: "memory");                                                           \
    __builtin_amdgcn_sched_barrier(0)

__global__ __launch_bounds__(NT,2) void rnn_cluster(
    const int*   __restrict__ x,
    const float* __restrict__ Wih0,
    const float* __restrict__ Whh0,
    const float* __restrict__ Wih1,
    const float* __restrict__ Whh1,
    const float* __restrict__ Wl,
    const float* __restrict__ bl,
    float*       __restrict__ out,
    int*         __restrict__ flags,  // (NCL, SS) zeroed per launch
    _Float16*    __restrict__ Hbuf)   // 2 layers x NCL x 2 bufs x 128x256 halfs
{
    __shared__ _Float16 wlds[3*6*8*64*8];          // 147456 B
    __shared__ unsigned long long bitsM[BTC];

    const int t   = threadIdx.x;
    const int c   = blockIdx.x & (NCL-1);
    const int j   = blockIdx.x >> 5;               // member 0..7
    const int L   = t & 63;
    const int w   = t >> 6;
    const int lm  = L & 15, quad = L >> 4;
    const int mp  = w >> 1, hv = w & 1;
    const int ucol = j*32 + hv*16 + lm;

    _Float16* H0 = Hbuf + (size_t)c*(2*BTC*HH);
    _Float16* H1 = Hbuf + (size_t)(NCL + c)*(2*BTC*HH);
    int* flg = flags + c*SS;

    // ---- pack weight slice into LDS (once) ----
    for (int idx = t; idx < 3*6*8*64; idx += NT){
        int lane = idx & 63;
        int kt   = (idx >> 6) & 7;
        int ntl  = (idx >> 9) % 6;
        int mat  = idx / 3072;
        const float* W = (mat==0) ? Whh0 : (mat==1) ? Wih1 : Whh1;
        int g  = (ntl>>1)*HH + j*32 + (ntl&1)*16 + (lane & 15);
        int kb = kt*32 + (lane>>4)*8;
        _Float16* d = wlds + (size_t)idx*8;
        #pragma unroll
        for (int e=0;e<8;++e) d[e] = (_Float16)W[g*HH + kb + e];
    }
    if (t < BTC){
        unsigned long long m = 0;
        const int* xr = x + (size_t)(c*BTC + t)*SS;
        for (int s=0;s<SS;++s) if (xr[s] > 0) m |= (1ull<<s);
        bitsM[t] = m;
    }

    float g0w[6];
    { int ug = ucol;
      g0w[0]=Wih0[ug*2+0];        g0w[1]=Wih0[ug*2+1];
      g0w[2]=Wih0[(ug+HH)*2+0];   g0w[3]=Wih0[(ug+HH)*2+1];
      g0w[4]=Wih0[(ug+2*HH)*2+0]; g0w[5]=Wih0[(ug+2*HH)*2+1]; }

    const int srow = j*16 + (t>>5);
    const int cs   = t & 31;
    float wl0[8], wl1[8];
    #pragma unroll
    for (int e=0;e<8;++e){ wl0[e]=Wl[cs*8+e]; wl1[e]=Wl[HH+cs*8+e]; }
    const float bl0=bl[0], bl1=bl[1];

    float hr0[2][4] = {}, hr1[2][4] = {};
    float amp=1.f, ph=0.f, nup=0.f, ndn=0.f;

    __syncthreads();

    // ---- interval 0: h0n(0)=h1n(0)=0 exactly (zero input, no bias) ----
    {
        _Float16* wp1 = H1 + (32*mp + 4*quad)*HH + ucol;
        #pragma unroll
        for (int m2=0;m2<2;++m2){
            #pragma unroll
            for (int reg=0;reg<4;++reg) stH(wp1 + (16*m2+reg)*HH, 0.f);
        }
        _Float16* wp0 = H0 + (BTC*HH) + (32*mp + 4*quad)*HH + ucol;
        #pragma unroll
        for (int m2=0;m2<2;++m2){
            #pragma unroll
            for (int reg=0;reg<4;++reg){
                int rowL = 32*mp + 16*m2 + 4*quad + reg;
                int bit = (int)(bitsM[rowL] & 1ull);
                float gr = bit?g0w[1]:g0w[0];
                float gz = bit?g0w[3]:g0w[2];
                float gn = bit?g0w[5]:g0w[4];
                float r = sigmoidf_(gr);
                float z = sigmoidf_(gz);
                float n = tanhf_(gn);
                float hnew = (1.f-z)*n;
                hr0[m2][reg] = hnew;
                stH(wp0 + (16*m2+reg)*HH, hnew);
            }
        }
    }
    asm volatile("s_waitcnt vmcnt(0)" ::: "memory");   // drain write-throughs to IC
    __syncthreads();
    if (t==0)
        __hip_atomic_fetch_add(&flg[0],1,__ATOMIC_RELAXED,__HIP_MEMORY_SCOPE_AGENT);

    for (int i=1;i<SS;++i){
        // ---- wait bar(i-1): publishes h0n(i), h1n(i-1) ----
        if (t==0){
            int guard=0;
            while(__hip_atomic_load(&flg[i-1],__ATOMIC_RELAXED,__HIP_MEMORY_SCOPE_AGENT) < CW){
                __builtin_amdgcn_s_sleep(1);
                if (++guard > (1<<20)) break;   // safety: never hang the harness
            }
        }
        __syncthreads();

        const int s = i-1;
        const _Float16* Hs0 = H0 + (i&1)*(BTC*HH)     + (32*mp + lm)*HH;
        const _Float16* Hs1 = H1 + ((i-1)&1)*(BTC*HH) + (32*mp + lm)*HH;

        // 1) sampling load (oldest in flight)
        half8 hvv = ldA16(H1 + (s&1)*(BTC*HH) + srow*HH + cs*8);

        // 2) chunk-a loads (kt 0..3): 16 in flight behind hvv
        half8 A0a[4][2], A1a[4][2];
        #pragma unroll
        for (int k2=0;k2<4;++k2){
            A0a[k2][0] = ldA16(Hs0 +         k2*32 + quad*8);
            A0a[k2][1] = ldA16(Hs0 + 16*HH + k2*32 + quad*8);
            A1a[k2][0] = ldA16(Hs1 +         k2*32 + quad*8);
            A1a[k2][1] = ldA16(Hs1 + 16*HH + k2*32 + quad*8);
        }

        // 3) wait for hvv only (16 still outstanding), do sampling math
        asm volatile("s_waitcnt vmcnt(16)" : "+v"(hvv) :: "memory");
        __builtin_amdgcn_sched_barrier(0);
        {
            float s0=0.f, s1=0.f;
            #pragma unroll
            for (int e=0;e<8;++e){ float f=(float)hvv[e]; s0+=f*wl0[e]; s1+=f*wl1[e]; }
            #pragma unroll
            for (int off=16; off>0; off>>=1){ s0+=__shfl_xor(s0,off,32); s1+=__shfl_xor(s1,off,32); }
            float l0=s0+bl0, l1=s1+bl1;
            bool  ev  = (s & 1) == 0;
            float low = -16.f + (float)(s>>1);
            float cnt = ev ? nup : ndn;
            float mocc = (16.f > cnt) ? 1.f : 0.f;
            float mun  = (low  < cnt) ? 1.f : 0.f;
            float mx = fmaxf(l0,l1);
            float e0 = __expf(l0-mx), e1 = __expf(l1-mx);
            float inv = __builtin_amdgcn_rcpf(e0+e1);
            float a0s = __builtin_amdgcn_sqrtf(e0*inv)*mun;
            float a1s = __builtin_amdgcn_sqrtf(e1*inv)*mocc;
            float nrm = __builtin_amdgcn_sqrtf(a0s*a0s + a1s*a1s);
            float den = fmaxf(nrm, 1e-12f);
            float rden = __builtin_amdgcn_rcpf(den);
            a0s*=rden; a1s*=rden;
            const float PI_F = 3.14159265358979323846f;
            float p0 = PI_F*l0*__builtin_amdgcn_rcpf(1.f+fabsf(l0));
            float p1 = PI_F*l1*__builtin_amdgcn_rcpf(1.f+fabsf(l1));
            int bit = (int)((bitsM[srow] >> s) & 1ull);
            amp *= bit ? a1s : a0s;
            ph  += bit ? p1 : p0;
            if (ev) nup += (float)bit; else ndn += (float)bit;
        }

        // 4) chunk-b loads (kt 4..7): 32 in flight total
        half8 A0b[4][2], A1b[4][2];
        #pragma unroll
        for (int k2=0;k2<4;++k2){
            int kt = 4+k2;
            A0b[k2][0] = ldA16(Hs0 +         kt*32 + quad*8);
            A0b[k2][1] = ldA16(Hs0 + 16*HH + kt*32 + quad*8);
            A1b[k2][0] = ldA16(Hs1 +         kt*32 + quad*8);
            A1b[k2][1] = ldA16(Hs1 + 16*HH + kt*32 + quad*8);
        }

        f32x4 a0n[3][2] = {};
        f32x4 aR[2]={}, aZ[2]={}, aNI[2]={}, aNH[2]={};

        // 5) chunk-a ready (b still flying under MFMA-a)
        WAIT_PIN_CHUNK("16", A0a, A1a);
        #pragma unroll
        for (int k2=0;k2<4;++k2){
            int kt = k2;
            half8 b0r = *(const half8*)(wlds + WOFF(0, 0+hv, kt) + L*8);
            half8 b0z = *(const half8*)(wlds + WOFF(0, 2+hv, kt) + L*8);
            half8 b0n = *(const half8*)(wlds + WOFF(0, 4+hv, kt) + L*8);
            half8 b1r = *(const half8*)(wlds + WOFF(1, 0+hv, kt) + L*8);
            half8 b1z = *(const half8*)(wlds + WOFF(1, 2+hv, kt) + L*8);
            half8 b1n = *(const half8*)(wlds + WOFF(1, 4+hv, kt) + L*8);
            half8 b2r = *(const half8*)(wlds + WOFF(2, 0+hv, kt) + L*8);
            half8 b2z = *(const half8*)(wlds + WOFF(2, 2+hv, kt) + L*8);
            half8 b2n = *(const half8*)(wlds + WOFF(2, 4+hv, kt) + L*8);
            #pragma unroll
            for (int m2=0;m2<2;++m2){
                a0n[0][m2] = __builtin_amdgcn_mfma_f32_16x16x32_f16(A0a[k2][m2], b0r, a0n[0][m2],0,0,0);
                a0n[1][m2] = __builtin_amdgcn_mfma_f32_16x16x32_f16(A0a[k2][m2], b0z, a0n[1][m2],0,0,0);
                a0n[2][m2] = __builtin_amdgcn_mfma_f32_16x16x32_f16(A0a[k2][m2], b0n, a0n[2][m2],0,0,0);
                aR [m2]    = __builtin_amdgcn_mfma_f32_16x16x32_f16(A0a[k2][m2], b1r, aR [m2],0,0,0);
                aZ [m2]    = __builtin_amdgcn_mfma_f32_16x16x32_f16(A0a[k2][m2], b1z, aZ [m2],0,0,0);
                aNI[m2]    = __builtin_amdgcn_mfma_f32_16x16x32_f16(A0a[k2][m2], b1n, aNI[m2],0,0,0);
                aR [m2]    = __builtin_amdgcn_mfma_f32_16x16x32_f16(A1a[k2][m2], b2r, aR [m2],0,0,0);
                aZ [m2]    = __builtin_amdgcn_mfma_f32_16x16x32_f16(A1a[k2][m2], b2z, aZ [m2],0,0,0);
                aNH[m2]    = __builtin_amdgcn_mfma_f32_16x16x32_f16(A1a[k2][m2], b2n, aNH[m2],0,0,0);
            }
        }

        // 6) chunk-b ready
        WAIT_PIN_CHUNK("0", A0b, A1b);
        #pragma unroll
        for (int k2=0;k2<4;++k2){
            int kt = 4+k2;
            half8 b0r = *(const half8*)(wlds + WOFF(0, 0+hv, kt) + L*8);
            half8 b0z = *(const half8*)(wlds + WOFF(0, 2+hv, kt) + L*8);
            half8 b0n = *(const half8*)(wlds + WOFF(0, 4+hv, kt) + L*8);
            half8 b1r = *(const half8*)(wlds + WOFF(1, 0+hv, kt) + L*8);
            half8 b1z = *(const half8*)(wlds + WOFF(1, 2+hv, kt) + L*8);
            half8 b1n = *(const half8*)(wlds + WOFF(1, 4+hv, kt) + L*8);
            half8 b2r = *(const half8*)(wlds + WOFF(2, 0+hv, kt) + L*8);
            half8 b2z = *(const half8*)(wlds + WOFF(2, 2+hv, kt) + L*8);
            half8 b2n = *(const half8*)(wlds + WOFF(2, 4+hv, kt) + L*8);
            #pragma unroll
            for (int m2=0;m2<2;++m2){
                a0n[0][m2] = __builtin_amdgcn_mfma_f32_16x16x32_f16(A0b[k2][m2], b0r, a0n[0][m2],0,0,0);
                a0n[1][m2] = __builtin_amdgcn_mfma_f32_16x16x32_f16(A0b[k2][m2], b0z, a0n[1][m2],0,0,0);
                a0n[2][m2] = __builtin_amdgcn_mfma_f32_16x16x32_f16(A0b[k2][m2], b0n, a0n[2][m2],0,0,0);
                aR [m2]    = __builtin_amdgcn_mfma_f32_16x16x32_f16(A0b[k2][m2], b1r, aR [m2],0,0,0);
                aZ [m2]    = __builtin_amdgcn_mfma_f32_16x16x32_f16(A0b[k2][m2], b1z, aZ [m2],0,0,0);
                aNI[m2]    = __builtin_amdgcn_mfma_f32_16x16x32_f16(A0b[k2][m2], b1n, aNI[m2],0,0,0);
                aR [m2]    = __builtin_amdgcn_mfma_f32_16x16x32_f16(A1b[k2][m2], b2r, aR [m2],0,0,0);
                aZ [m2]    = __builtin_amdgcn_mfma_f32_16x16x32_f16(A1b[k2][m2], b2z, aZ [m2],0,0,0);
                aNH[m2]    = __builtin_amdgcn_mfma_f32_16x16x32_f16(A1b[k2][m2], b2n, aNH[m2],0,0,0);
            }
        }

        // ---- ew1(i): h1n(i) -> H1[i&1] ----
        {
            _Float16* wp = H1 + (i&1)*(BTC*HH) + (32*mp + 4*quad)*HH + ucol;
            #pragma unroll
            for (int m2=0;m2<2;++m2){
                #pragma unroll
                for (int reg=0;reg<4;++reg){
                    float r = sigmoidf_(aR[m2][reg]);
                    float z = sigmoidf_(aZ[m2][reg]);
                    float n = tanhf_(aNI[m2][reg] + r*aNH[m2][reg]);
                    float hnew = (1.f-z)*n + z*hr1[m2][reg];
                    hr1[m2][reg] = hnew;
                    stH(wp + (16*m2 + reg)*HH, hnew);
                }
            }
        }

        // ---- ew0(i+1): h0n(i+1) -> H0[(i+1)&1] ----
        if (i < SS-1){
            _Float16* wp = H0 + ((i+1)&1)*(BTC*HH) + (32*mp + 4*quad)*HH + ucol;
            #pragma unroll
            for (int m2=0;m2<2;++m2){
                #pragma unroll
                for (int reg=0;reg<4;++reg){
                    int rowL = 32*mp + 16*m2 + 4*quad + reg;
                    int bit = (int)((bitsM[rowL] >> i) & 1ull);
                    float gr = bit?g0w[1]:g0w[0];
                    float gz = bit?g0w[3]:g0w[2];
                    float gn = bit?g0w[5]:g0w[4];
                    float r = sigmoidf_(gr + a0n[0][m2][reg]);
                    float z = sigmoidf_(gz + a0n[1][m2][reg]);
                    float n = tanhf_(gn + r*a0n[2][m2][reg]);
                    float hnew = (1.f-z)*n + z*hr0[m2][reg];
                    hr0[m2][reg] = hnew;
                    stH(wp + (16*m2 + reg)*HH, hnew);
                }
            }
        }

        // ---- arrive bar(i): publishes h1n(i), h0n(i+1) ----
        asm volatile("s_waitcnt vmcnt(0)" ::: "memory");   // write-throughs at IC
        __syncthreads();
        if (t==0)
            __hip_atomic_fetch_add(&flg[i],1,__ATOMIC_RELAXED,__HIP_MEMORY_SCOPE_AGENT);
    }

    // ---- epilogue: wait bar(63), sampling(63) ----
    if (t==0){
        int guard=0;
        while(__hip_atomic_load(&flg[SS-1],__ATOMIC_RELAXED,__HIP_MEMORY_SCOPE_AGENT) < CW){
            __builtin_amdgcn_s_sleep(1);
            if (++guard > (1<<20)) break;
        }
    }
    __syncthreads();
    {
        const int s = SS-1;
        half8 hvv = ldA16(H1 + (s&1)*(BTC*HH) + srow*HH + cs*8);
        asm volatile("s_waitcnt vmcnt(0)" : "+v"(hvv) :: "memory");
        __builtin_amdgcn_sched_barrier(0);
        float s0=0.f, s1=0.f;
        #pragma unroll
        for (int e=0;e<8;++e){ float f=(float)hvv[e]; s0+=f*wl0[e]; s1+=f*wl1[e]; }
        #pragma unroll
        for (int off=16; off>0; off>>=1){ s0+=__shfl_xor(s0,off,32); s1+=__shfl_xor(s1,off,32); }
        float l0=s0+bl0, l1=s1+bl1;
        bool  ev  = (s & 1) == 0;
        float low = -16.f + (float)(s>>1);
        float cnt = ev ? nup : ndn;
        float mocc = (16.f > cnt) ? 1.f : 0.f;
        float mun  = (low  < cnt) ? 1.f : 0.f;
        float mx = fmaxf(l0,l1);
        float e0 = __expf(l0-mx), e1 = __expf(l1-mx);
        float inv = __builtin_amdgcn_rcpf(e0+e1);
        float a0s = __builtin_amdgcn_sqrtf(e0*inv)*mun;
        float a1s = __builtin_amdgcn_sqrtf(e1*inv)*mocc;
        float nrm = __builtin_amdgcn_sqrtf(a0s*a0s + a1s*a1s);
        float den = fmaxf(nrm, 1e-12f);
        float rden = __builtin_amdgcn_rcpf(den);
        a0s*=rden; a1s*=rden;
        const float PI_F = 3.14159265358979323846f;
        float p0 = PI_F*l0*__builtin_amdgcn_rcpf(1.f+fabsf(l0));
        float p1 = PI_F*l1*__builtin_amdgcn_rcpf(1.f+fabsf(l1));
        int bit = (int)((bitsM[srow] >> s) & 1ull);
        amp *= bit ? a1s : a0s;
        ph  += bit ? p1 : p0;
    }
    if (cs == 0) out[c*BTC + srow] = amp * cosf(ph);
}

extern "C" void kernel_launch(void* const* d_in, const int* in_sizes, int n_in,
                              void* d_out, int out_size, void* d_ws, size_t ws_size,
                              hipStream_t stream) {
    (void)in_sizes; (void)n_in; (void)out_size; (void)ws_size;
    const int*   x    = (const int*)d_in[0];
    const float* Wih0 = (const float*)d_in[1];
    const float* Whh0 = (const float*)d_in[2];
    const float* Wih1 = (const float*)d_in[3];
    const float* Whh1 = (const float*)d_in[4];
    const float* Wl   = (const float*)d_in[5];
    const float* bl   = (const float*)d_in[6];

    int*      flags = (int*)d_ws;                         // 8 KB used, 64 KB reserved
    _Float16* Hbuf  = (_Float16*)((char*)d_ws + 65536);   // 8 MB h state

    zero_flags<<<(NCL*SS + 255)/256, 256, 0, stream>>>(flags);
    rnn_cluster<<<NCL*CW, NT, 0, stream>>>(x, Wih0, Whh0, Wih1, Whh1, Wl, bl,
                                           (float*)d_out, flags, Hbuf);
}